// Round 12
// baseline (65.290 us; speedup 1.0000x reference)
//
#include <hip/hip_runtime.h>
#include <hip/hip_bf16.h>

typedef __attribute__((ext_vector_type(4))) int intx4;
typedef __attribute__((ext_vector_type(8))) int intx8;
typedef __attribute__((ext_vector_type(16))) float floatx16;

#define B_ROWS 8192
#define DIM 128
#define NPAIR 4095
#define NSLOT 32
// rows scaled by sqrt(log2(e)) so S_mfma = S * log2(e) and exp(S) = exp2(S_mfma)
#define RSCALE 1.2011224087864498f

#define GLOAD_LDS16(gp, lp)                                                     \
    __builtin_amdgcn_global_load_lds(                                           \
        (const __attribute__((address_space(1))) void*)(gp),                    \
        (__attribute__((address_space(3))) void*)(lp), 16, 0, 0)

// ---------------- zero Z (fallback path only) ----------------
__global__ void kzero(float* __restrict__ Z) {
    int i = blockIdx.x * 256 + threadIdx.x;
    if (i < B_ROWS) Z[i] = 0.f;
}

// ------------- prep: normalize rows -> fp8 e4m3 (scaled), exact pair dots -------------
// 1024 blocks x 256 thr; wave W handles rows 2W (lanes 0-31) and 2W+1 (lanes 32-63);
// lane loads float4. Pair (2W, 2W+1) dot computed via cross-half shuffle, exact fp32.
__global__ void kprep(const float* __restrict__ X, unsigned char* __restrict__ XN,
                      float* __restrict__ pairT, float* __restrict__ out) {
    const int wid = threadIdx.x >> 6;
    const int lane = threadIdx.x & 63;
    const int j = lane & 31;
    const int W = blockIdx.x * 4 + wid;  // wave index == pair index
    const int row = 2 * W + (lane >> 5);

    const float4 v = *reinterpret_cast<const float4*>(X + row * DIM + j * 4);
    float ss = v.x * v.x + v.y * v.y + v.z * v.z + v.w * v.w;
    #pragma unroll
    for (int m = 1; m < 32; m <<= 1) ss += __shfl_xor(ss, m, 64);  // within half
    const float rn = ss > 0.f ? rsqrtf(ss) : 0.f;

    // exact pair similarity: dot(raw_this, raw_partner) * rn * rn_partner
    float4 pv;
    pv.x = __shfl_xor(v.x, 32, 64);
    pv.y = __shfl_xor(v.y, 32, 64);
    pv.z = __shfl_xor(v.z, 32, 64);
    pv.w = __shfl_xor(v.w, 32, 64);
    float pd = v.x * pv.x + v.y * pv.y + v.z * pv.z + v.w * pv.w;
    #pragma unroll
    for (int m = 1; m < 32; m <<= 1) pd += __shfl_xor(pd, m, 64);
    const float rno = __shfl_xor(rn, 32, 64);
    if (lane == 0 && W < NPAIR) pairT[W] = pd * rn * rno;

    // fp8 write: normalized * sqrt(log2 e)
    const float sc = rn * RSCALE;
    int pk = __builtin_amdgcn_cvt_pk_fp8_f32(v.x * sc, v.y * sc, 0, false);
    pk = __builtin_amdgcn_cvt_pk_fp8_f32(v.z * sc, v.w * sc, pk, true);
    reinterpret_cast<int*>(XN)[row * 32 + j] = pk;

    if (W == 0 && lane == 0) out[0] = 0.f;
}

// ---- stage one 64-col x 128-K fp8 slab (8KB) to LDS ----
// LDS[col][kb] linear; source pre-swizzled with kb ^= ((col&7)<<4) so the
// swizzled ds_read is conflict-free. 2 DMA loads per thread per slab.
__device__ __forceinline__ void stage64(const unsigned char* __restrict__ gsrc,
                                        unsigned char* lbuf, int tid) {
    #pragma unroll
    for (int it = 0; it < 2; ++it) {
        const int off = it * 4096 + tid * 16;  // wave-uniform base + lane*16
        const int src = (off & ~127) | ((off & 127) ^ (((off >> 7) & 7) << 4));
        GLOAD_LDS16(gsrc + src, lbuf + off);
    }
}

// ------------- main: fp8 MX GEMM, A in regs, B 3-buffer counted-vmcnt LDS -------------
// grid (16, 64): y = row panel rb (128 rows), x = col group g (512 cols = 8 slabs).
// 4 waves 2x2 (wr rows-half, wc cols-half); wave = 64 rows x 32 cols per phase.
// Per phase: 2x mfma_scale_f32_32x32x64_f8f6f4 chained over K=128 per row-tile.
template <bool USEP>
__global__ void __launch_bounds__(256, 2) kgemm(const unsigned char* __restrict__ XN,
                                                float* __restrict__ ZP) {
    __shared__ unsigned char Bs[3][64 * DIM];  // 3 x 8KB

    const int tid = threadIdx.x;
    const int wid = tid >> 6;
    const int lane = tid & 63;
    const int l31 = lane & 31;
    const int hi = lane >> 5;
    const int wr = wid >> 1;
    const int wc = wid & 1;
    const int rb = blockIdx.y;
    const int g = blockIdx.x;

    // ---- A: 64 rows in regs: a[kk][t], row = rb*128 + wr*64 + t*32 + l31,
    //      bytes [kk*64 + hi*32, +32)  (one MX block of 32 per lane) ----
    intx8 a[2][2];
    #pragma unroll
    for (int t = 0; t < 2; ++t) {
        const unsigned char* Ab =
            XN + (size_t)(rb * 128 + wr * 64 + t * 32 + l31) * DIM + hi * 32;
        #pragma unroll
        for (int kk = 0; kk < 2; ++kk)
            a[kk][t] = *reinterpret_cast<const intx8*>(Ab + kk * 64);
    }

    float rp[2][16];
    #pragma unroll
    for (int t = 0; t < 2; ++t)
        #pragma unroll
        for (int q = 0; q < 16; ++q) rp[t][q] = 0.f;

    const floatx16 z16 = {0.f, 0.f, 0.f, 0.f, 0.f, 0.f, 0.f, 0.f,
                          0.f, 0.f, 0.f, 0.f, 0.f, 0.f, 0.f, 0.f};

    // prologue: stage slabs 0,1
    stage64(XN + (size_t)(g * 512) * DIM, Bs[0], tid);
    stage64(XN + (size_t)(g * 512 + 64) * DIM, Bs[1], tid);

    const int rblk = (rb * 128 + wr * 64) >> 6;  // wave's 64-row block index

    for (int t = 0; t < 8; ++t) {
        // counted wait: slab t landed (2 loads), slab t+1 stays in flight
        if (t < 7)
            asm volatile("s_waitcnt vmcnt(2)" ::: "memory");
        else
            asm volatile("s_waitcnt vmcnt(0)" ::: "memory");
        __builtin_amdgcn_s_barrier();  // raw barrier, no drain

        if (t + 2 < 8)
            stage64(XN + (size_t)(g * 512 + (t + 2) * 64) * DIM, Bs[(t + 2) % 3], tid);

        const unsigned char* Bt = Bs[t % 3];
        const int cbase = g * 512 + t * 64;
        const int lcol = wc * 32 + l31;

        __builtin_amdgcn_s_setprio(1);
        // B frags: B[k][col] = XN[col][k]; lane: col = lcol, k-block hi*32 (+kk*64)
        intx8 b[2];
        #pragma unroll
        for (int kk = 0; kk < 2; ++kk) {
            const int base = kk * 64 + hi * 32;
            const int sw = (lcol & 7) << 4;
            const intx4 lo =
                *reinterpret_cast<const intx4*>(&Bt[lcol * 128 + (base ^ sw)]);
            const intx4 hi4 =
                *reinterpret_cast<const intx4*>(&Bt[lcol * 128 + ((base + 16) ^ sw)]);
            b[kk] = __builtin_shufflevector(lo, hi4, 0, 1, 2, 3, 4, 5, 6, 7);
        }

        floatx16 acc[2];
        #pragma unroll
        for (int tt = 0; tt < 2; ++tt) {
            acc[tt] = __builtin_amdgcn_mfma_scale_f32_32x32x64_f8f6f4(
                a[0][tt], b[0], z16, 0, 0, 0, 0x7F, 0, 0x7F);
            acc[tt] = __builtin_amdgcn_mfma_scale_f32_32x32x64_f8f6f4(
                a[1][tt], b[1], acc[tt], 0, 0, 0, 0x7F, 0, 0x7F);
        }
        __builtin_amdgcn_s_setprio(0);

        // epilogue: exp2, exclude diagonal on the aligned slab, accumulate
        if ((cbase >> 6) == rblk) {
            const int ccol = cbase + wc * 32 + l31;
            #pragma unroll
            for (int tt = 0; tt < 2; ++tt)
                #pragma unroll
                for (int q = 0; q < 16; ++q) {
                    const int rrow = rb * 128 + wr * 64 + tt * 32 +
                                     (q & 3) + 8 * (q >> 2) + 4 * hi;
                    float e = __builtin_amdgcn_exp2f(acc[tt][q]);
                    if (rrow == ccol) e = 0.f;
                    rp[tt][q] += e;
                }
        } else {
            #pragma unroll
            for (int tt = 0; tt < 2; ++tt)
                #pragma unroll
                for (int q = 0; q < 16; ++q)
                    rp[tt][q] += __builtin_amdgcn_exp2f(acc[tt][q]);
        }
    }

    // ---- row sums: reduce over the 32 lanes sharing a row (lane&31) ----
    #pragma unroll
    for (int tt = 0; tt < 2; ++tt)
        #pragma unroll
        for (int q = 0; q < 16; ++q) {
            float v = rp[tt][q];
            v += __shfl_xor(v, 1, 64);
            v += __shfl_xor(v, 2, 64);
            v += __shfl_xor(v, 4, 64);
            v += __shfl_xor(v, 8, 64);
            v += __shfl_xor(v, 16, 64);
            if (l31 == 0) {
                const int row = rb * 128 + wr * 64 + tt * 32 +
                                (q & 3) + 8 * (q >> 2) + 4 * hi;
                if (USEP)
                    ZP[(g * 2 + wc) * B_ROWS + row] = v;
                else
                    atomicAdd(&ZP[row], v);
            }
        }
}

// ------------- final (P path): Z[r] = sum_{32 slots}; loss reduce -------------
__global__ void kfinalP(const float* __restrict__ P, const float* __restrict__ pairT,
                        float* __restrict__ out) {
    const int r = blockIdx.x * 256 + threadIdx.x;
    float s = 0.f;
    if (r < B_ROWS - 2) {
        float z = 0.f;
        #pragma unroll
        for (int tt = 0; tt < NSLOT; ++tt) z += P[tt * B_ROWS + r];
        s = logf(z);
    }
    if (r < NPAIR) s -= 2.f * pairT[r];
    #pragma unroll
    for (int m = 1; m < 64; m <<= 1) s += __shfl_xor(s, m, 64);
    __shared__ float red[4];
    const int wid = threadIdx.x >> 6;
    const int lane = threadIdx.x & 63;
    if (lane == 0) red[wid] = s;
    __syncthreads();
    if (threadIdx.x == 0) {
        float tsum = red[0] + red[1] + red[2] + red[3];
        atomicAdd(out, tsum / (float)B_ROWS);
    }
}

// ------------- final (Z fallback path) -------------
__global__ void kfinalZ(const float* __restrict__ Z, const float* __restrict__ pairT,
                        float* __restrict__ out) {
    float s = 0.f;
    for (int r = threadIdx.x; r < B_ROWS - 2; r += 1024) s += logf(Z[r]);
    for (int p = threadIdx.x; p < NPAIR; p += 1024) s -= 2.f * pairT[p];
    #pragma unroll
    for (int m = 1; m < 64; m <<= 1) s += __shfl_xor(s, m, 64);
    __shared__ float red[16];
    const int wid = threadIdx.x >> 6;
    const int lane = threadIdx.x & 63;
    if (lane == 0) red[wid] = s;
    __syncthreads();
    if (threadIdx.x == 0) {
        float t = 0.f;
        #pragma unroll
        for (int i = 0; i < 16; ++i) t += red[i];
        out[0] = t / (float)B_ROWS;
    }
}

extern "C" void kernel_launch(void* const* d_in, const int* in_sizes, int n_in,
                              void* d_out, int out_size, void* d_ws, size_t ws_size,
                              hipStream_t stream) {
    (void)in_sizes; (void)n_in; (void)out_size;
    const float* X = (const float*)d_in[0];
    float* out = (float*)d_out;
    char* ws = (char*)d_ws;

    float* Z = (float*)ws;                                   // 32 KB (fallback)
    float* pairT = (float*)(ws + 32768);                     // 16 KB
    unsigned char* XN = (unsigned char*)(ws + 49152);        // 1 MB fp8
    float* P = (float*)(ws + 49152 + 1048576);               // 1 MB (32 x 8192 f32)
    const size_t need = 49152 + 1048576 + (size_t)NSLOT * B_ROWS * 4;
    const bool useP = ws_size >= need;

    kprep<<<1024, 256, 0, stream>>>(X, XN, pairT, out);
    if (useP) {
        kgemm<true><<<dim3(16, 64), 256, 0, stream>>>(XN, P);
        kfinalP<<<32, 256, 0, stream>>>(P, pairT, out);
    } else {
        kzero<<<32, 256, 0, stream>>>(Z);
        kgemm<false><<<dim3(16, 64), 256, 0, stream>>>(XN, Z);
        kfinalZ<<<1, 1024, 0, stream>>>(Z, pairT, out);
    }
}

// Round 13
// 33.995 us; speedup vs baseline: 1.9206x; 1.9206x over previous
//
#include <hip/hip_runtime.h>
#include <hip/hip_bf16.h>

typedef __attribute__((ext_vector_type(8))) short short8;
typedef __attribute__((ext_vector_type(4))) float floatx4;

#define B_ROWS 8192
#define DIM 128
#define NPAIR 4095
// rows scaled by sqrt(log2(e)) so S_mfma = S * log2(e) and exp(S) = exp2(S_mfma)
#define RSCALE 1.2011224087864498f

#define GLOAD_LDS16(gp, lp)                                                     \
    __builtin_amdgcn_global_load_lds(                                           \
        (const __attribute__((address_space(1))) void*)(gp),                    \
        (__attribute__((address_space(3))) void*)(lp), 16, 0, 0)

// ---------------- zero Z (fallback path only) ----------------
__global__ void kzero(float* __restrict__ Z) {
    int i = blockIdx.x * 256 + threadIdx.x;
    if (i < B_ROWS) Z[i] = 0.f;
}

// ------------- fused prep: normalize rows -> bf16 (scaled), pair dots, zero out -------------
__global__ void kprep(const float* __restrict__ X, __hip_bfloat16* __restrict__ XN,
                      float* __restrict__ pairT, float* __restrict__ out) {
    __shared__ float2 lds[4][64];
    const int wid = threadIdx.x >> 6;
    const int lane = threadIdx.x & 63;
    const int row = blockIdx.x * 4 + wid;

    const float2 v = *reinterpret_cast<const float2*>(X + row * DIM + lane * 2);
    float ss = v.x * v.x + v.y * v.y;
    #pragma unroll
    for (int m = 1; m < 64; m <<= 1) ss += __shfl_xor(ss, m, 64);
    const float rn = ss > 0.f ? rsqrtf(ss) : 0.f;
    const float2 nv = make_float2(v.x * rn, v.y * rn);

    *reinterpret_cast<__hip_bfloat162*>(XN + row * DIM + lane * 2) =
        __float22bfloat162_rn(make_float2(nv.x * RSCALE, nv.y * RSCALE));
    lds[wid][lane] = nv;  // unscaled for exact pair dot
    __syncthreads();

    if ((wid & 1) == 0) {
        const int p = blockIdx.x * 2 + (wid >> 1);
        if (p < NPAIR) {
            const float2 a = lds[wid][lane];
            const float2 b = lds[wid + 1][lane];
            float d = a.x * b.x + a.y * b.y;
            #pragma unroll
            for (int m = 1; m < 64; m <<= 1) d += __shfl_xor(d, m, 64);
            if (lane == 0) pairT[p] = d;
        }
    }
    if (blockIdx.x == 0 && threadIdx.x == 0) out[0] = 0.f;
}

// ---- stage one 64x128 bf16 half-slab to LDS (linear dest, pre-swizzled source) ----
__device__ __forceinline__ void stage_half(const __hip_bfloat16* __restrict__ gsrc,
                                           __hip_bfloat16* lbuf, int tid) {
    const int wid = tid >> 6;
    const int lane = tid & 63;
    #pragma unroll
    for (int it = 0; it < 4; ++it) {
        const int woff = it * 2048 + wid * 512;  // wave-uniform elem offset
        const int e = woff + lane * 8;
        const int src = (e & ~127) | ((e & 127) ^ (((e >> 7) & 7) << 3));
        GLOAD_LDS16(gsrc + src, lbuf + woff);
    }
}

// 8 ds_read_b128 of next slab's B fragments (swizzled cols)
#define LOADB(BN, BUF)                                                          \
    {                                                                           \
        const __hip_bfloat16* Bn_ = (BUF);                                      \
        _Pragma("unroll")                                                       \
        for (int n_ = 0; n_ < 2; ++n_) {                                        \
            const int row_ = wc * 32 + n_ * 16 + lr;                            \
            _Pragma("unroll")                                                   \
            for (int kk_ = 0; kk_ < 4; ++kk_) {                                 \
                const int col_ = (kk_ * 32 + lk * 8) ^ ((row_ & 7) << 3);       \
                BN[kk_][n_] =                                                   \
                    *reinterpret_cast<const short8*>(&Bn_[row_ * DIM + col_]);  \
            }                                                                   \
        }                                                                       \
    }

// exp + accumulate of a finished phase TE (runs in the MFMA shadow of phase TE+1)
#define EXPACC(AP, TE)                                                          \
    {                                                                           \
        const int cbj_ = g * 8 + ((TE) >> 1);                                   \
        const bool dz_ = (cbj_ == rb) && (((TE) & 1) == wr);                    \
        if (dz_) {                                                              \
            _Pragma("unroll")                                                   \
            for (int m_ = 0; m_ < 4; ++m_)                                      \
                _Pragma("unroll")                                               \
                for (int n_ = 0; n_ < 2; ++n_)                                  \
                    _Pragma("unroll")                                           \
                    for (int r_ = 0; r_ < 4; ++r_) {                            \
                        float e_ = __builtin_amdgcn_exp2f(AP[m_][n_][r_]);      \
                        if (m_ * 16 + lk * 4 + r_ == wc * 32 + n_ * 16 + lr)    \
                            e_ = 0.f;                                           \
                        rp[m_][r_] += e_;                                       \
                    }                                                           \
        } else {                                                                \
            _Pragma("unroll")                                                   \
            for (int m_ = 0; m_ < 4; ++m_)                                      \
                _Pragma("unroll")                                               \
                for (int n_ = 0; n_ < 2; ++n_)                                  \
                    _Pragma("unroll")                                           \
                    for (int r_ = 0; r_ < 4; ++r_)                              \
                        rp[m_][r_] += __builtin_amdgcn_exp2f(AP[m_][n_][r_]);   \
        }                                                                       \
    }

// one pipeline phase: AC = fresh acc, AP = prev acc (exp'd here), BC = current
// B frags (loaded last phase), BN = next B frags (loaded here, used next phase)
#define PHASE(AC, AP, BC, BN, T, DOEXP)                                         \
    {                                                                           \
        asm volatile("s_waitcnt vmcnt(0)" ::: "memory");                        \
        __builtin_amdgcn_s_barrier();                                           \
        __builtin_amdgcn_sched_barrier(0);                                      \
        if ((T) + 2 < 16)                                                       \
            stage_half(XN + ((size_t)(g * 8 + (((T) + 2) >> 1)) * 128 +         \
                             (((T) + 2) & 1) * 64) * DIM,                       \
                       Bs[((T) + 2) % 3], tid);                                 \
        if ((T) + 1 < 16) LOADB(BN, Bs[((T) + 1) % 3]);                         \
        _Pragma("unroll")                                                       \
        for (int m_ = 0; m_ < 4; ++m_)                                          \
            _Pragma("unroll")                                                   \
            for (int n_ = 0; n_ < 2; ++n_)                                      \
                AC[m_][n_] = __builtin_amdgcn_mfma_f32_16x16x32_bf16(           \
                    a[0][m_], BC[0][n_], zero4, 0, 0, 0);                       \
        _Pragma("unroll")                                                       \
        for (int kk_ = 1; kk_ < 4; ++kk_)                                       \
            _Pragma("unroll")                                                   \
            for (int m_ = 0; m_ < 4; ++m_)                                      \
                _Pragma("unroll")                                               \
                for (int n_ = 0; n_ < 2; ++n_)                                  \
                    AC[m_][n_] = __builtin_amdgcn_mfma_f32_16x16x32_bf16(       \
                        a[kk_][m_], BC[kk_][n_], AC[m_][n_], 0, 0, 0);          \
        if (DOEXP) EXPACC(AP, (T) - 1);                                         \
    }

// ------------- main: row-panel GEMM, interleaved 3-buffer pipeline -------------
// grid (8, 64): y = row panel rb (128 rows), x = col group g (8 tiles = 16 slabs).
// 4 waves 2x2. Per phase t: vmcnt(0) [usually satisfied] -> raw barrier ->
// stage slab t+2 (DMA) -> ds_read slab t+1 frags (hides under MFMA) ->
// 32 MFMA on slab t (operands pre-loaded) -> exp of slab t-1 (in MFMA shadow).
template <bool USEP>
__global__ void __launch_bounds__(256, 2) kgemm(const __hip_bfloat16* __restrict__ XN,
                                                float* __restrict__ ZP) {
    __shared__ __hip_bfloat16 Bs[3][64 * DIM];

    const int tid = threadIdx.x;
    const int wid = tid >> 6;
    const int lane = tid & 63;
    const int lr = lane & 15;
    const int lk = lane >> 4;
    const int wr = wid >> 1;
    const int wc = wid & 1;
    const int rb = blockIdx.y;
    const int g = blockIdx.x;

    // A: 64 rows in registers: a[kk][m], rows rb*128 + wr*64 + m*16 + lr
    short8 a[4][4];
    const __hip_bfloat16* Abase = XN + (rb * 128 + wr * 64 + lr) * DIM + lk * 8;
    #pragma unroll
    for (int m = 0; m < 4; ++m)
        #pragma unroll
        for (int kk = 0; kk < 4; ++kk)
            a[kk][m] = *reinterpret_cast<const short8*>(Abase + m * 16 * DIM + kk * 32);

    float rp[4][4];
    #pragma unroll
    for (int m = 0; m < 4; ++m)
        #pragma unroll
        for (int r = 0; r < 4; ++r) rp[m][r] = 0.f;

    const floatx4 zero4 = {0.f, 0.f, 0.f, 0.f};
    short8 bA[4][2], bB[4][2];
    floatx4 accA[4][2], accB[4][2];

    // prologue: stage slabs 0,1; read slab-0 fragments
    stage_half(XN + (size_t)(g * 8) * 128 * DIM, Bs[0], tid);
    stage_half(XN + ((size_t)(g * 8) * 128 + 64) * DIM, Bs[1], tid);
    asm volatile("s_waitcnt vmcnt(4)" ::: "memory");  // slab 0 landed
    __builtin_amdgcn_s_barrier();
    __builtin_amdgcn_sched_barrier(0);
    LOADB(bA, Bs[0]);

    for (int t = 0; t < 16; t += 2) {
        PHASE(accA, accB, bA, bB, t, (t > 0));
        PHASE(accB, accA, bB, bA, t + 1, true);
    }
    EXPACC(accB, 15);  // final pending phase

    // ---- row sums: reduce over lr, store slot (g*2 + wc) ----
    #pragma unroll
    for (int m = 0; m < 4; ++m)
        #pragma unroll
        for (int r = 0; r < 4; ++r) {
            float v = rp[m][r];
            v += __shfl_xor(v, 1, 64);
            v += __shfl_xor(v, 2, 64);
            v += __shfl_xor(v, 4, 64);
            v += __shfl_xor(v, 8, 64);
            if (lr == 0) {
                const int row = rb * 128 + wr * 64 + m * 16 + lk * 4 + r;
                if (USEP)
                    ZP[(g * 2 + wc) * B_ROWS + row] = v;
                else
                    atomicAdd(&ZP[row], v);
            }
        }
}

// ------------- final (P path): Z[r] = sum_{16 slots} P[t][r]; loss reduce -------------
__global__ void kfinalP(const float* __restrict__ P, const float* __restrict__ pairT,
                        float* __restrict__ out) {
    const int r = blockIdx.x * 256 + threadIdx.x;
    float s = 0.f;
    if (r < B_ROWS - 2) {
        float z = 0.f;
        #pragma unroll
        for (int tt = 0; tt < 16; ++tt) z += P[tt * B_ROWS + r];
        s = logf(z);
    }
    if (r < NPAIR) s -= 2.f * pairT[r];
    #pragma unroll
    for (int m = 1; m < 64; m <<= 1) s += __shfl_xor(s, m, 64);
    __shared__ float red[4];
    const int wid = threadIdx.x >> 6;
    const int lane = threadIdx.x & 63;
    if (lane == 0) red[wid] = s;
    __syncthreads();
    if (threadIdx.x == 0) {
        float tsum = red[0] + red[1] + red[2] + red[3];
        atomicAdd(out, tsum / (float)B_ROWS);
    }
}

// ------------- final (Z fallback path) -------------
__global__ void kfinalZ(const float* __restrict__ Z, const float* __restrict__ pairT,
                        float* __restrict__ out) {
    float s = 0.f;
    for (int r = threadIdx.x; r < B_ROWS - 2; r += 1024) s += logf(Z[r]);
    for (int p = threadIdx.x; p < NPAIR; p += 1024) s -= 2.f * pairT[p];
    #pragma unroll
    for (int m = 1; m < 64; m <<= 1) s += __shfl_xor(s, m, 64);
    __shared__ float red[16];
    const int wid = threadIdx.x >> 6;
    const int lane = threadIdx.x & 63;
    if (lane == 0) red[wid] = s;
    __syncthreads();
    if (threadIdx.x == 0) {
        float t = 0.f;
        #pragma unroll
        for (int i = 0; i < 16; ++i) t += red[i];
        out[0] = t / (float)B_ROWS;
    }
}

extern "C" void kernel_launch(void* const* d_in, const int* in_sizes, int n_in,
                              void* d_out, int out_size, void* d_ws, size_t ws_size,
                              hipStream_t stream) {
    (void)in_sizes; (void)n_in; (void)out_size;
    const float* X = (const float*)d_in[0];
    float* out = (float*)d_out;
    char* ws = (char*)d_ws;

    float* Z = (float*)ws;                                   // 32 KB
    float* pairT = (float*)(ws + 32768);                     // 16 KB
    __hip_bfloat16* XN = (__hip_bfloat16*)(ws + 49152);      // 2 MB
    float* P = (float*)(ws + 49152 + 2097152);               // 512 KB (16 x 8192 f32)
    const size_t need = 49152 + 2097152 + (size_t)16 * B_ROWS * 4;
    const bool useP = ws_size >= need;

    kprep<<<2048, 256, 0, stream>>>(X, XN, pairT, out);
    if (useP) {
        kgemm<true><<<dim3(8, 64), 256, 0, stream>>>(XN, P);
        kfinalP<<<32, 256, 0, stream>>>(P, pairT, out);
    } else {
        kzero<<<32, 256, 0, stream>>>(Z);
        kgemm<false><<<dim3(8, 64), 256, 0, stream>>>(XN, Z);
        kfinalZ<<<1, 1024, 0, stream>>>(Z, pairT, out);
    }
}